// Round 19
// baseline (90.350 us; speedup 1.0000x reference)
//
#include <hip/hip_runtime.h>
#include <hip/hip_bf16.h>

// Problem constants
#define BATCH 2
#define SEQ   2048
#define EMBD  1024
#define NHEAD 16
#define HDIM  64
#define N3    3072           // 3*EMBD
#define MTOT  4096           // BATCH*SEQ
#define KDIM  1024

typedef __attribute__((ext_vector_type(8))) short  short8;   // 8 x bf16 (4 VGPRs)
typedef __attribute__((ext_vector_type(4))) short  s16x4;
typedef __attribute__((ext_vector_type(4))) float  f32x4;

__device__ __forceinline__ short f2bfs(float f) {
    return __builtin_bit_cast(short, __float2bfloat16(f));   // compiler emits v_cvt_pk_bf16_f32 for pairs
}

// ---------------------------------------------------------------- cast x -> bf16
__global__ __launch_bounds__(256) void cast_x_kernel(const float* __restrict__ x,
                                                     short* __restrict__ xb, int n4) {
    int i = blockIdx.x * 256 + threadIdx.x;
    if (i >= n4) return;
    float4 f = reinterpret_cast<const float4*>(x)[i];
    s16x4 o;
    o[0] = f2bfs(f.x); o[1] = f2bfs(f.y);
    o[2] = f2bfs(f.z); o[3] = f2bfs(f.w);
    reinterpret_cast<s16x4*>(xb)[i] = o;
}

// ------------------------------------------- cast + transpose w [K,N3] -> wt [N3,K]
__global__ __launch_bounds__(256) void cast_wt_kernel(const float* __restrict__ w,
                                                      short* __restrict__ wt) {
    __shared__ float tile[32][33];
    int n0 = blockIdx.x * 32;   // N3/32 = 96
    int k0 = blockIdx.y * 32;   // K/32  = 32
    int tx = threadIdx.x & 31;
    int ty = threadIdx.x >> 5;  // 0..7
#pragma unroll
    for (int i = 0; i < 4; ++i)
        tile[ty + i * 8][tx] = w[(size_t)(k0 + ty + i * 8) * N3 + n0 + tx];
    __syncthreads();
#pragma unroll
    for (int i = 0; i < 4; ++i)
        wt[(size_t)(n0 + ty + i * 8) * KDIM + k0 + tx] = f2bfs(tile[tx][ty + i * 8]);
}

// ---------------------------------------------------------------- QKV GEMM
// 2-phase 128² with DEPTH-2 PREFETCH: triple-buffered LDS ring (48KB, still
// 3 blocks/CU for the 768 grid). stage(t+2) issued each iter; vmcnt(8) retires
// stage(t) while t+1/t+2 (8 loads) stay in flight -> ~2 compute-tiles (~1400cy)
// of latency hiding, covering per-XCD B-panel L3 misses (B set 6MB > 4MB L2).
// WAR: stage target = buffer computed LAST iteration, protected by exit barrier.
__device__ __forceinline__ void stage_tile(const short* gbase, short* lbase, int tid) {
#pragma unroll
    for (int c = 0; c < 2; ++c) {
        int row = c * 64 + (tid >> 2);
        int chunk = (tid & 3) ^ ((row >> 1) & 3);    // inverse-swizzled source
        const short* gp = gbase + (size_t)row * KDIM + chunk * 8;
        short* lp = lbase + c * 2048 + tid * 8;      // linear dest: row, slot tid&3
        __builtin_amdgcn_global_load_lds((const __attribute__((address_space(1))) void*)gp,
                                         (__attribute__((address_space(3))) void*)lp,
                                         16, 0, 0);
    }
}

__device__ __forceinline__ void gemm_step(const short* lAc, const short* lBc,
                                          int wm, int wn, int arow, f32x4 (&acc)[4][4]) {
    short8 a[4], b[4];
#pragma unroll
    for (int im = 0; im < 4; ++im)
        a[im] = *(const short8*)&lAc[(wm * 64 + im * 16) * 32 + arow];
#pragma unroll
    for (int in = 0; in < 4; ++in)
        b[in] = *(const short8*)&lBc[(wn * 64 + in * 16) * 32 + arow];
#pragma unroll
    for (int im = 0; im < 4; ++im)
#pragma unroll
        for (int in = 0; in < 4; ++in)
            acc[im][in] = __builtin_amdgcn_mfma_f32_16x16x32_bf16(a[im], b[in], acc[im][in], 0, 0, 0);
}

__global__ __launch_bounds__(256) void qkv_gemm_kernel(const short* __restrict__ xb,
                                                       const short* __restrict__ wt,
                                                       short* __restrict__ qb,
                                                       short* __restrict__ kbuf,
                                                       short* __restrict__ vt) {
    __shared__ short lA[3][128 * 32];
    __shared__ short lB[3][128 * 32];

    const int tid  = threadIdx.x;
    const int lane = tid & 63;
    const int wid  = tid >> 6;
    const int wm = wid >> 1, wn = wid & 1;
    const int lid = blockIdx.x;
    const int swz = (lid & 7) * 96 + (lid >> 3);
    const int m0 = (swz / 24) * 128;
    const int n0 = (swz % 24) * 128;

    f32x4 acc[4][4];
#pragma unroll
    for (int i = 0; i < 4; ++i)
#pragma unroll
        for (int j = 0; j < 4; ++j) acc[i][j] = (f32x4){0.f, 0.f, 0.f, 0.f};

    const short* gA = xb + (size_t)m0 * KDIM;
    const short* gB = wt + (size_t)n0 * KDIM;

    // prologue: tiles 0,1 staged (8 loads outstanding)
    stage_tile(gA,      lA[0], tid);
    stage_tile(gB,      lB[0], tid);
    stage_tile(gA + 32, lA[1], tid);
    stage_tile(gB + 32, lB[1], tid);

    short* pa0 = lA[0]; short* pa1 = lA[1]; short* pa2 = lA[2];
    short* pb0 = lB[0]; short* pb1 = lB[1]; short* pb2 = lB[2];

    const int arow = (lane & 15) * 32 + (((lane >> 4) ^ ((lane >> 1) & 3)) * 8);
#pragma unroll 1
    for (int kt = 0; kt < KDIM / 32; ++kt) {
        if (kt + 2 < KDIM / 32) {
            stage_tile(gA + (kt + 2) * 32, pa2, tid);
            stage_tile(gB + (kt + 2) * 32, pb2, tid);
            asm volatile("s_waitcnt vmcnt(8)" ::: "memory");   // stage(kt) retired; kt+1,kt+2 in flight
        } else if (kt + 1 < KDIM / 32) {
            asm volatile("s_waitcnt vmcnt(4)" ::: "memory");   // stage(kt) retired; kt+1 in flight
        } else {
            asm volatile("s_waitcnt vmcnt(0)" ::: "memory");
        }
        __builtin_amdgcn_s_barrier();
        __builtin_amdgcn_sched_barrier(0);
        gemm_step(pa0, pb0, wm, wn, arow, acc);
        __builtin_amdgcn_sched_barrier(0);
        __builtin_amdgcn_s_barrier();                          // WAR: reads of pa0 done before it becomes stage target
        short* ta = pa0; pa0 = pa1; pa1 = pa2; pa2 = ta;
        short* tb = pb0; pb0 = pb1; pb1 = pb2; pb2 = tb;
    }

    // epilogue: scatter to q*0.125 [B,H,T,D], k [B,H,T,D], v^T [B,H,D,T]
#pragma unroll
    for (int im = 0; im < 4; ++im) {
        int t0m = m0 + wm * 64 + im * 16 + (lane >> 4) * 4;
        int b = t0m >> 11;
        int t0 = t0m & 2047;
#pragma unroll
        for (int in = 0; in < 4; ++in) {
            int col = n0 + wn * 64 + in * 16 + (lane & 15);
            int which = col >> 10;
            int h = (col >> 6) & 15;
            int d = col & 63;
            if (which == 2) {
                s16x4 pk;
#pragma unroll
                for (int r = 0; r < 4; ++r) pk[r] = f2bfs(acc[im][in][r]);
                *(s16x4*)&vt[((size_t)(b * NHEAD + h) * HDIM + d) * SEQ + t0] = pk;
            } else {
                short* dst = (which == 0) ? qb : kbuf;
                float sc = (which == 0) ? 0.125f : 1.0f;   // fold 1/sqrt(D) into Q (exact pow2)
#pragma unroll
                for (int r = 0; r < 4; ++r)
                    dst[((size_t)(b * NHEAD + h) * SEQ + t0 + r) * HDIM + d] = f2bfs(acc[im][in][r] * sc);
            }
        }
    }
}

// ---------------------------------------------------------------- flash attention (R18 best, unchanged)
// KVB=128, 512 blocks x 512 threads (8 waves, 128 q-rows); 2 blocks/CU.
// Balanced pairing {15-ps, ps}: 17 tiles/CU uniform. V swizzle 4-bit (d&15):
// conflicts 0. Heads XCD-pinned. SWAPPED QK^T with permuted K rows -> lane-local
// P values are exactly the PV B-frags (P never leaves registers).
#define KVB 128

__device__ __forceinline__ int swzf(int r) { return (r & 3) ^ (((r >> 2) & 3) << 1); }

__device__ __forceinline__ void stage_kv(const short* kh, const short* vh, int kb,
                                         short* lk, short* lv, int tid) {
#pragma unroll
    for (int c = 0; c < 2; ++c) {
        int row = c * 64 + (tid >> 3);               // 0..127
        int sch = (tid & 7) ^ swzf(row);
        const short* gk = kh + (size_t)(kb + row) * HDIM + sch * 8;
        __builtin_amdgcn_global_load_lds((const __attribute__((address_space(1))) void*)gk,
                                         (__attribute__((address_space(3))) void*)(lk + c * 4096 + tid * 8), 16, 0, 0);
    }
#pragma unroll
    for (int c = 0; c < 2; ++c) {
        int d = c * 32 + (tid >> 4);                 // 0..63
        int sch = (tid & 15) ^ (d & 15);             // 4-bit chunk swizzle
        const short* gv = vh + (size_t)d * SEQ + kb + sch * 8;
        __builtin_amdgcn_global_load_lds((const __attribute__((address_space(1))) void*)gv,
                                         (__attribute__((address_space(3))) void*)(lv + c * 4096 + tid * 8), 16, 0, 0);
    }
}

struct AttnState {
    f32x4 o[4];
    float mrun, lrun;
};

__device__ __forceinline__ void compute_tile(const short* lk, const short* lv, int kb,
                                             int qbase, int qrow, int rbase, int hi,
                                             const short8* aQ, const short8& vone,
                                             AttnState& st) {
    const float L2E = 1.4426950408889634f;
    f32x4 s[8];
    __builtin_amdgcn_s_setprio(1);
#pragma unroll
    for (int nb = 0; nb < 8; ++nb) {
        int kidx = (nb & 3) * 32 + (rbase >> 2) * 8 + (nb >> 2) * 4 + (rbase & 3);
        f32x4 a = (f32x4){0.f, 0.f, 0.f, 0.f};
#pragma unroll
        for (int c = 0; c < 2; ++c) {
            int slot2 = (c * 4 + hi) ^ swzf(kidx);
            short8 bK = *(const short8*)&lk[kidx * 64 + slot2 * 8];
            a = __builtin_amdgcn_mfma_f32_16x16x32_bf16(bK, aQ[c], a, 0, 0, 0);
        }
        s[nb] = a;
    }
    __builtin_amdgcn_s_setprio(0);
    if (kb + KVB - 1 > qbase) {
#pragma unroll
        for (int nb = 0; nb < 8; ++nb) {
            int keyb = kb + (nb & 3) * 32 + hi * 8 + (nb >> 2) * 4;
#pragma unroll
            for (int r = 0; r < 4; ++r)
                if (keyb + r > qrow) s[nb][r] = -1e30f;
        }
    }
    float pm = -INFINITY;
#pragma unroll
    for (int nb = 0; nb < 8; ++nb)
        pm = fmaxf(pm, fmaxf(fmaxf(s[nb][0], s[nb][1]), fmaxf(s[nb][2], s[nb][3])));
    pm = fmaxf(pm, __shfl_xor(pm, 16));
    pm = fmaxf(pm, __shfl_xor(pm, 32));
    if (__any(pm > st.mrun + 8.0f)) {
        float mnew = fmaxf(st.mrun, pm);
        float sf = exp2f((st.mrun - mnew) * L2E);
        st.mrun = mnew;
        st.lrun *= sf;
#pragma unroll
        for (int dt = 0; dt < 4; ++dt)
#pragma unroll
            for (int r = 0; r < 4; ++r) st.o[dt][r] *= sf;
    }
    float mterm = st.mrun * L2E;
    short8 bp[4];
#pragma unroll
    for (int c = 0; c < 4; ++c)
#pragma unroll
        for (int jj = 0; jj < 8; ++jj) {
            float p = exp2f(fmaf(s[c + (jj >> 2) * 4][jj & 3], L2E, -mterm));
            bp[c][jj] = f2bfs(p);
        }
    f32x4 osum = (f32x4){0.f, 0.f, 0.f, 0.f};
    __builtin_amdgcn_s_setprio(1);
#pragma unroll
    for (int dt = 0; dt < 4; ++dt) {
        int d = dt * 16 + rbase;
#pragma unroll
        for (int c = 0; c < 4; ++c) {
            int slot2 = (c * 4 + hi) ^ (d & 15);     // 4-bit chunk swizzle
            short8 bV = *(const short8*)&lv[d * 128 + slot2 * 8];
            st.o[dt] = __builtin_amdgcn_mfma_f32_16x16x32_bf16(bV, bp[c], st.o[dt], 0, 0, 0);
        }
    }
#pragma unroll
    for (int c = 0; c < 4; ++c)
        osum = __builtin_amdgcn_mfma_f32_16x16x32_bf16(vone, bp[c], osum, 0, 0, 0);
    __builtin_amdgcn_s_setprio(0);
    st.lrun += osum[0];
}

__global__ __launch_bounds__(512, 4) void attn_kernel(const short* __restrict__ q,
                                                      const short* __restrict__ kk,
                                                      const short* __restrict__ vtg,
                                                      float* __restrict__ out) {
    const int tid  = threadIdx.x;
    const int lane = tid & 63;
    const int wid  = tid >> 6;                       // 0..7
    const int lid  = blockIdx.x;                     // 0..511
    const int xcd  = lid & 7;
    const int v    = lid >> 3;                       // 0..63
    const int h4   = v & 3;                          // head rank on this XCD
    const int ps   = (v >> 2) & 7;                   // CU pair-slot
    const int half = v >> 5;                         // 0 = long half (first)
    const int qt   = half ? ps : (15 - ps);          // balanced pair {15-ps, ps}
    const int bh   = h4 * 8 + xcd;                   // pinned to XCD
    const int rbase = lane & 15;                     // my q-row within wave tile
    const int hi    = lane >> 4;

    const short* qh = q   + (size_t)bh * SEQ * HDIM;
    const short* kh = kk  + (size_t)bh * SEQ * HDIM;
    const short* vh = vtg + (size_t)bh * HDIM * SEQ;

    __shared__ short lK[2][KVB * 64];
    __shared__ short lV[2][HDIM * KVB];

    short8 vone;
#pragma unroll
    for (int jj = 0; jj < 8; ++jj) vone[jj] = (short)0x3F80;   // bf16 1.0

    const int b = bh >> 4, h = bh & 15;

    const int qbase = qt * 128 + wid * 16;
    const int qrow  = qbase + rbase;

    short8 aQ[2];
#pragma unroll
    for (int c = 0; c < 2; ++c)
        aQ[c] = *(const short8*)&qh[(size_t)qrow * HDIM + c * 32 + hi * 8];

    AttnState st;
#pragma unroll
    for (int i = 0; i < 4; ++i) st.o[i] = (f32x4){0.f, 0.f, 0.f, 0.f};
    st.mrun = -INFINITY;
    st.lrun = 0.f;

    const int ktiles = qt + 1;
    stage_kv(kh, vh, 0, lK[0], lV[0], tid);
#pragma unroll 1
    for (int t = 0; t < ktiles; t += 2) {
        {   // ---- even tile: compute lK[0]/lV[0], stage t+1 -> buf1
            const int kb = t * KVB;
            if (t + 1 < ktiles) {
                stage_kv(kh, vh, kb + KVB, lK[1], lV[1], tid);
                asm volatile("s_waitcnt vmcnt(4)" ::: "memory");
            } else {
                asm volatile("s_waitcnt vmcnt(0)" ::: "memory");
            }
            __builtin_amdgcn_s_barrier();
            __builtin_amdgcn_sched_barrier(0);
            if (kb < qbase + 16)
                compute_tile(lK[0], lV[0], kb, qbase, qrow, rbase, hi, aQ, vone, st);
            __builtin_amdgcn_sched_barrier(0);
            __builtin_amdgcn_s_barrier();
        }
        if (t + 1 < ktiles) {   // ---- odd tile: compute lK[1]/lV[1], stage t+2 -> buf0
            const int kb = (t + 1) * KVB;
            if (t + 2 < ktiles) {
                stage_kv(kh, vh, kb + KVB, lK[0], lV[0], tid);
                asm volatile("s_waitcnt vmcnt(4)" ::: "memory");
            } else {
                asm volatile("s_waitcnt vmcnt(0)" ::: "memory");
            }
            __builtin_amdgcn_s_barrier();
            __builtin_amdgcn_sched_barrier(0);
            if (kb < qbase + 16)
                compute_tile(lK[1], lV[1], kb, qbase, qrow, rbase, hi, aQ, vone, st);
            __builtin_amdgcn_sched_barrier(0);
            __builtin_amdgcn_s_barrier();
        }
    }

    float inv = 1.0f / st.lrun;
#pragma unroll
    for (int dt = 0; dt < 4; ++dt) {
        f32x4 ov;
#pragma unroll
        for (int r = 0; r < 4; ++r) ov[r] = st.o[dt][r] * inv;
        *(f32x4*)&out[((size_t)(b * SEQ + qrow) * NHEAD + h) * HDIM + dt * 16 + hi * 4] = ov;
    }
}

// ---------------------------------------------------------------- launch
extern "C" void kernel_launch(void* const* d_in, const int* in_sizes, int n_in,
                              void* d_out, int out_size, void* d_ws, size_t ws_size,
                              hipStream_t stream) {
    const float* x = (const float*)d_in[0];
    const float* w = (const float*)d_in[1];
    float* out = (float*)d_out;

    char* ws = (char*)d_ws;
    short* xb   = (short*)(ws);                            // 8 MB  [M,K] bf16
    short* wt   = (short*)(ws + (size_t)8  * 1024 * 1024); // 6 MB  [N3,K] bf16
    short* qb   = (short*)(ws + (size_t)14 * 1024 * 1024); // 8 MB  [B,H,T,D] (pre-scaled 0.125)
    short* kbuf = (short*)(ws + (size_t)22 * 1024 * 1024); // 8 MB  [B,H,T,D]
    short* vt   = (short*)(ws + (size_t)30 * 1024 * 1024); // 8 MB  [B,H,D,T]

    cast_x_kernel<<<dim3(MTOT * KDIM / 4 / 256), dim3(256), 0, stream>>>(x, xb, MTOT * KDIM / 4);
    cast_wt_kernel<<<dim3(N3 / 32, KDIM / 32), dim3(256), 0, stream>>>(w, wt);
    qkv_gemm_kernel<<<dim3(768), dim3(256), 0, stream>>>(xb, wt, qb, kbuf, vt);
    attn_kernel<<<dim3(512), dim3(512), 0, stream>>>(qb, kbuf, vt, out);
}

// Round 20
// 87.927 us; speedup vs baseline: 1.0276x; 1.0276x over previous
//
#include <hip/hip_runtime.h>
#include <hip/hip_bf16.h>

// Problem constants
#define BATCH 2
#define SEQ   2048
#define EMBD  1024
#define NHEAD 16
#define HDIM  64
#define N3    3072           // 3*EMBD
#define MTOT  4096           // BATCH*SEQ
#define KDIM  1024

typedef __attribute__((ext_vector_type(8))) short  short8;   // 8 x bf16 (4 VGPRs)
typedef __attribute__((ext_vector_type(4))) short  s16x4;
typedef __attribute__((ext_vector_type(4))) float  f32x4;

__device__ __forceinline__ short f2bfs(float f) {
    return __builtin_bit_cast(short, __float2bfloat16(f));   // compiler emits v_cvt_pk_bf16_f32 for pairs
}

// ---------------------------------------------------------------- fused casts
// blocks 0..4095: x fp32 -> xb bf16 (vectorized float4 -> short4)
// blocks 4096..7167: w [K,N3] fp32 -> wt [N3,K] bf16 (32x32 LDS transpose)
__global__ __launch_bounds__(256) void cast_fused_kernel(const float* __restrict__ x,
                                                         short* __restrict__ xb,
                                                         const float* __restrict__ w,
                                                         short* __restrict__ wt) {
    __shared__ float tile[32][33];
    const int bid = blockIdx.x;
    if (bid < 4096) {
        int i = bid * 256 + threadIdx.x;             // n4 = 1048576 = 4096*256 exact
        float4 f = reinterpret_cast<const float4*>(x)[i];
        s16x4 o;
        o[0] = f2bfs(f.x); o[1] = f2bfs(f.y);
        o[2] = f2bfs(f.z); o[3] = f2bfs(f.w);
        reinterpret_cast<s16x4*>(xb)[i] = o;
    } else {
        int b2 = bid - 4096;                         // 0..3071 = 96 x 32
        int n0 = (b2 % 96) * 32;
        int k0 = (b2 / 96) * 32;
        int tx = threadIdx.x & 31;
        int ty = threadIdx.x >> 5;                   // 0..7
#pragma unroll
        for (int i = 0; i < 4; ++i)
            tile[ty + i * 8][tx] = w[(size_t)(k0 + ty + i * 8) * N3 + n0 + tx];
        __syncthreads();
#pragma unroll
        for (int i = 0; i < 4; ++i)
            wt[(size_t)(n0 + ty + i * 8) * KDIM + k0 + tx] = f2bfs(tile[tx][ty + i * 8]);
    }
}

// ---------------------------------------------------------------- QKV GEMM
// 2-phase 128² (best measured), unroll-2 buffer bodies, counted vmcnt(4),
// LDS XOR-swizzle, XCD-bijective block swizzle.
__device__ __forceinline__ void stage_tile(const short* gbase, short* lbase, int tid) {
#pragma unroll
    for (int c = 0; c < 2; ++c) {
        int row = c * 64 + (tid >> 2);
        int chunk = (tid & 3) ^ ((row >> 1) & 3);    // inverse-swizzled source
        const short* gp = gbase + (size_t)row * KDIM + chunk * 8;
        short* lp = lbase + c * 2048 + tid * 8;      // linear dest: row, slot tid&3
        __builtin_amdgcn_global_load_lds((const __attribute__((address_space(1))) void*)gp,
                                         (__attribute__((address_space(3))) void*)lp,
                                         16, 0, 0);
    }
}

__device__ __forceinline__ void gemm_step(const short* lAc, const short* lBc,
                                          int wm, int wn, int arow, f32x4 (&acc)[4][4]) {
    short8 a[4], b[4];
#pragma unroll
    for (int im = 0; im < 4; ++im)
        a[im] = *(const short8*)&lAc[(wm * 64 + im * 16) * 32 + arow];
#pragma unroll
    for (int in = 0; in < 4; ++in)
        b[in] = *(const short8*)&lBc[(wn * 64 + in * 16) * 32 + arow];
#pragma unroll
    for (int im = 0; im < 4; ++im)
#pragma unroll
        for (int in = 0; in < 4; ++in)
            acc[im][in] = __builtin_amdgcn_mfma_f32_16x16x32_bf16(a[im], b[in], acc[im][in], 0, 0, 0);
}

__global__ __launch_bounds__(256) void qkv_gemm_kernel(const short* __restrict__ xb,
                                                       const short* __restrict__ wt,
                                                       short* __restrict__ qb,
                                                       short* __restrict__ kbuf,
                                                       short* __restrict__ vt) {
    __shared__ short lA[2][128 * 32];
    __shared__ short lB[2][128 * 32];

    const int tid  = threadIdx.x;
    const int lane = tid & 63;
    const int wid  = tid >> 6;
    const int wm = wid >> 1, wn = wid & 1;
    const int lid = blockIdx.x;
    const int swz = (lid & 7) * 96 + (lid >> 3);
    const int m0 = (swz / 24) * 128;
    const int n0 = (swz % 24) * 128;

    f32x4 acc[4][4];
#pragma unroll
    for (int i = 0; i < 4; ++i)
#pragma unroll
        for (int j = 0; j < 4; ++j) acc[i][j] = (f32x4){0.f, 0.f, 0.f, 0.f};

    const short* gA = xb + (size_t)m0 * KDIM;
    const short* gB = wt + (size_t)n0 * KDIM;

    stage_tile(gA, lA[0], tid);
    stage_tile(gB, lB[0], tid);

    const int arow = (lane & 15) * 32 + (((lane >> 4) ^ ((lane >> 1) & 3)) * 8);
#pragma unroll 1
    for (int kt = 0; kt < KDIM / 32; kt += 2) {
        {   // ---- even: compute buf0, stage kt+1 -> buf1
            if (kt + 1 < KDIM / 32) {
                stage_tile(gA + (kt + 1) * 32, lA[1], tid);
                stage_tile(gB + (kt + 1) * 32, lB[1], tid);
                asm volatile("s_waitcnt vmcnt(4)" ::: "memory");
            } else {
                asm volatile("s_waitcnt vmcnt(0)" ::: "memory");
            }
            __builtin_amdgcn_s_barrier();
            __builtin_amdgcn_sched_barrier(0);
            gemm_step(lA[0], lB[0], wm, wn, arow, acc);
            __builtin_amdgcn_sched_barrier(0);
            __builtin_amdgcn_s_barrier();
        }
        {   // ---- odd: compute buf1, stage kt+2 -> buf0
            if (kt + 2 < KDIM / 32) {
                stage_tile(gA + (kt + 2) * 32, lA[0], tid);
                stage_tile(gB + (kt + 2) * 32, lB[0], tid);
                asm volatile("s_waitcnt vmcnt(4)" ::: "memory");
            } else {
                asm volatile("s_waitcnt vmcnt(0)" ::: "memory");
            }
            __builtin_amdgcn_s_barrier();
            __builtin_amdgcn_sched_barrier(0);
            gemm_step(lA[1], lB[1], wm, wn, arow, acc);
            __builtin_amdgcn_sched_barrier(0);
            __builtin_amdgcn_s_barrier();
        }
    }

    // epilogue: scatter to q*0.125 [B,H,T,D], k [B,H,T,D], v^T [B,H,D,T]
#pragma unroll
    for (int im = 0; im < 4; ++im) {
        int t0m = m0 + wm * 64 + im * 16 + (lane >> 4) * 4;
        int b = t0m >> 11;
        int t0 = t0m & 2047;
#pragma unroll
        for (int in = 0; in < 4; ++in) {
            int col = n0 + wn * 64 + in * 16 + (lane & 15);
            int which = col >> 10;
            int h = (col >> 6) & 15;
            int d = col & 63;
            if (which == 2) {
                s16x4 pk;
#pragma unroll
                for (int r = 0; r < 4; ++r) pk[r] = f2bfs(acc[im][in][r]);
                *(s16x4*)&vt[((size_t)(b * NHEAD + h) * HDIM + d) * SEQ + t0] = pk;
            } else {
                short* dst = (which == 0) ? qb : kbuf;
                float sc = (which == 0) ? 0.125f : 1.0f;   // fold 1/sqrt(D) into Q (exact pow2)
#pragma unroll
                for (int r = 0; r < 4; ++r)
                    dst[((size_t)(b * NHEAD + h) * SEQ + t0 + r) * HDIM + d] = f2bfs(acc[im][in][r] * sc);
            }
        }
    }
}

// ---------------------------------------------------------------- flash attention (R18 best, unchanged)
// KVB=128, 512 blocks x 512 threads (8 waves, 128 q-rows); 2 blocks/CU.
// Balanced pairing {15-ps, ps}: 17 tiles/CU uniform. V swizzle 4-bit (d&15):
// conflicts 0. Heads XCD-pinned. SWAPPED QK^T with permuted K rows -> lane-local
// P values are exactly the PV B-frags (P never leaves registers).
#define KVB 128

__device__ __forceinline__ int swzf(int r) { return (r & 3) ^ (((r >> 2) & 3) << 1); }

__device__ __forceinline__ void stage_kv(const short* kh, const short* vh, int kb,
                                         short* lk, short* lv, int tid) {
#pragma unroll
    for (int c = 0; c < 2; ++c) {
        int row = c * 64 + (tid >> 3);               // 0..127
        int sch = (tid & 7) ^ swzf(row);
        const short* gk = kh + (size_t)(kb + row) * HDIM + sch * 8;
        __builtin_amdgcn_global_load_lds((const __attribute__((address_space(1))) void*)gk,
                                         (__attribute__((address_space(3))) void*)(lk + c * 4096 + tid * 8), 16, 0, 0);
    }
#pragma unroll
    for (int c = 0; c < 2; ++c) {
        int d = c * 32 + (tid >> 4);                 // 0..63
        int sch = (tid & 15) ^ (d & 15);             // 4-bit chunk swizzle
        const short* gv = vh + (size_t)d * SEQ + kb + sch * 8;
        __builtin_amdgcn_global_load_lds((const __attribute__((address_space(1))) void*)gv,
                                         (__attribute__((address_space(3))) void*)(lv + c * 4096 + tid * 8), 16, 0, 0);
    }
}

struct AttnState {
    f32x4 o[4];
    float mrun, lrun;
};

__device__ __forceinline__ void compute_tile(const short* lk, const short* lv, int kb,
                                             int qbase, int qrow, int rbase, int hi,
                                             const short8* aQ, const short8& vone,
                                             AttnState& st) {
    const float L2E = 1.4426950408889634f;
    f32x4 s[8];
    __builtin_amdgcn_s_setprio(1);
#pragma unroll
    for (int nb = 0; nb < 8; ++nb) {
        int kidx = (nb & 3) * 32 + (rbase >> 2) * 8 + (nb >> 2) * 4 + (rbase & 3);
        f32x4 a = (f32x4){0.f, 0.f, 0.f, 0.f};
#pragma unroll
        for (int c = 0; c < 2; ++c) {
            int slot2 = (c * 4 + hi) ^ swzf(kidx);
            short8 bK = *(const short8*)&lk[kidx * 64 + slot2 * 8];
            a = __builtin_amdgcn_mfma_f32_16x16x32_bf16(bK, aQ[c], a, 0, 0, 0);
        }
        s[nb] = a;
    }
    __builtin_amdgcn_s_setprio(0);
    if (kb + KVB - 1 > qbase) {
#pragma unroll
        for (int nb = 0; nb < 8; ++nb) {
            int keyb = kb + (nb & 3) * 32 + hi * 8 + (nb >> 2) * 4;
#pragma unroll
            for (int r = 0; r < 4; ++r)
                if (keyb + r > qrow) s[nb][r] = -1e30f;
        }
    }
    float pm = -INFINITY;
#pragma unroll
    for (int nb = 0; nb < 8; ++nb)
        pm = fmaxf(pm, fmaxf(fmaxf(s[nb][0], s[nb][1]), fmaxf(s[nb][2], s[nb][3])));
    pm = fmaxf(pm, __shfl_xor(pm, 16));
    pm = fmaxf(pm, __shfl_xor(pm, 32));
    if (__any(pm > st.mrun + 8.0f)) {
        float mnew = fmaxf(st.mrun, pm);
        float sf = exp2f((st.mrun - mnew) * L2E);
        st.mrun = mnew;
        st.lrun *= sf;
#pragma unroll
        for (int dt = 0; dt < 4; ++dt)
#pragma unroll
            for (int r = 0; r < 4; ++r) st.o[dt][r] *= sf;
    }
    float mterm = st.mrun * L2E;
    short8 bp[4];
#pragma unroll
    for (int c = 0; c < 4; ++c)
#pragma unroll
        for (int jj = 0; jj < 8; ++jj) {
            float p = exp2f(fmaf(s[c + (jj >> 2) * 4][jj & 3], L2E, -mterm));
            bp[c][jj] = f2bfs(p);
        }
    f32x4 osum = (f32x4){0.f, 0.f, 0.f, 0.f};
    __builtin_amdgcn_s_setprio(1);
#pragma unroll
    for (int dt = 0; dt < 4; ++dt) {
        int d = dt * 16 + rbase;
#pragma unroll
        for (int c = 0; c < 4; ++c) {
            int slot2 = (c * 4 + hi) ^ (d & 15);     // 4-bit chunk swizzle
            short8 bV = *(const short8*)&lv[d * 128 + slot2 * 8];
            st.o[dt] = __builtin_amdgcn_mfma_f32_16x16x32_bf16(bV, bp[c], st.o[dt], 0, 0, 0);
        }
    }
#pragma unroll
    for (int c = 0; c < 4; ++c)
        osum = __builtin_amdgcn_mfma_f32_16x16x32_bf16(vone, bp[c], osum, 0, 0, 0);
    __builtin_amdgcn_s_setprio(0);
    st.lrun += osum[0];
}

__global__ __launch_bounds__(512, 4) void attn_kernel(const short* __restrict__ q,
                                                      const short* __restrict__ kk,
                                                      const short* __restrict__ vtg,
                                                      float* __restrict__ out) {
    const int tid  = threadIdx.x;
    const int lane = tid & 63;
    const int wid  = tid >> 6;                       // 0..7
    const int lid  = blockIdx.x;                     // 0..511
    const int xcd  = lid & 7;
    const int v    = lid >> 3;                       // 0..63
    const int h4   = v & 3;                          // head rank on this XCD
    const int ps   = (v >> 2) & 7;                   // CU pair-slot
    const int half = v >> 5;                         // 0 = long half (first)
    const int qt   = half ? ps : (15 - ps);          // balanced pair {15-ps, ps}
    const int bh   = h4 * 8 + xcd;                   // pinned to XCD
    const int rbase = lane & 15;                     // my q-row within wave tile
    const int hi    = lane >> 4;

    const short* qh = q   + (size_t)bh * SEQ * HDIM;
    const short* kh = kk  + (size_t)bh * SEQ * HDIM;
    const short* vh = vtg + (size_t)bh * HDIM * SEQ;

    __shared__ short lK[2][KVB * 64];
    __shared__ short lV[2][HDIM * KVB];

    short8 vone;
#pragma unroll
    for (int jj = 0; jj < 8; ++jj) vone[jj] = (short)0x3F80;   // bf16 1.0

    const int b = bh >> 4, h = bh & 15;

    const int qbase = qt * 128 + wid * 16;
    const int qrow  = qbase + rbase;

    short8 aQ[2];
#pragma unroll
    for (int c = 0; c < 2; ++c)
        aQ[c] = *(const short8*)&qh[(size_t)qrow * HDIM + c * 32 + hi * 8];

    AttnState st;
#pragma unroll
    for (int i = 0; i < 4; ++i) st.o[i] = (f32x4){0.f, 0.f, 0.f, 0.f};
    st.mrun = -INFINITY;
    st.lrun = 0.f;

    const int ktiles = qt + 1;
    stage_kv(kh, vh, 0, lK[0], lV[0], tid);
#pragma unroll 1
    for (int t = 0; t < ktiles; t += 2) {
        {   // ---- even tile: compute lK[0]/lV[0], stage t+1 -> buf1
            const int kb = t * KVB;
            if (t + 1 < ktiles) {
                stage_kv(kh, vh, kb + KVB, lK[1], lV[1], tid);
                asm volatile("s_waitcnt vmcnt(4)" ::: "memory");
            } else {
                asm volatile("s_waitcnt vmcnt(0)" ::: "memory");
            }
            __builtin_amdgcn_s_barrier();
            __builtin_amdgcn_sched_barrier(0);
            if (kb < qbase + 16)
                compute_tile(lK[0], lV[0], kb, qbase, qrow, rbase, hi, aQ, vone, st);
            __builtin_amdgcn_sched_barrier(0);
            __builtin_amdgcn_s_barrier();
        }
        if (t + 1 < ktiles) {   // ---- odd tile: compute lK[1]/lV[1], stage t+2 -> buf0
            const int kb = (t + 1) * KVB;
            if (t + 2 < ktiles) {
                stage_kv(kh, vh, kb + KVB, lK[0], lV[0], tid);
                asm volatile("s_waitcnt vmcnt(4)" ::: "memory");
            } else {
                asm volatile("s_waitcnt vmcnt(0)" ::: "memory");
            }
            __builtin_amdgcn_s_barrier();
            __builtin_amdgcn_sched_barrier(0);
            if (kb < qbase + 16)
                compute_tile(lK[1], lV[1], kb, qbase, qrow, rbase, hi, aQ, vone, st);
            __builtin_amdgcn_sched_barrier(0);
            __builtin_amdgcn_s_barrier();
        }
    }

    float inv = 1.0f / st.lrun;
#pragma unroll
    for (int dt = 0; dt < 4; ++dt) {
        f32x4 ov;
#pragma unroll
        for (int r = 0; r < 4; ++r) ov[r] = st.o[dt][r] * inv;
        *(f32x4*)&out[((size_t)(b * SEQ + qrow) * NHEAD + h) * HDIM + dt * 16 + hi * 4] = ov;
    }
}

// ---------------------------------------------------------------- launch
extern "C" void kernel_launch(void* const* d_in, const int* in_sizes, int n_in,
                              void* d_out, int out_size, void* d_ws, size_t ws_size,
                              hipStream_t stream) {
    const float* x = (const float*)d_in[0];
    const float* w = (const float*)d_in[1];
    float* out = (float*)d_out;

    char* ws = (char*)d_ws;
    short* xb   = (short*)(ws);                            // 8 MB  [M,K] bf16
    short* wt   = (short*)(ws + (size_t)8  * 1024 * 1024); // 6 MB  [N3,K] bf16
    short* qb   = (short*)(ws + (size_t)14 * 1024 * 1024); // 8 MB  [B,H,T,D] (pre-scaled 0.125)
    short* kbuf = (short*)(ws + (size_t)22 * 1024 * 1024); // 8 MB  [B,H,T,D]
    short* vt   = (short*)(ws + (size_t)30 * 1024 * 1024); // 8 MB  [B,H,D,T]

    cast_fused_kernel<<<dim3(4096 + 3072), dim3(256), 0, stream>>>(x, xb, w, wt);
    qkv_gemm_kernel<<<dim3(768), dim3(256), 0, stream>>>(xb, wt, qb, kbuf, vt);
    attn_kernel<<<dim3(512), dim3(512), 0, stream>>>(qb, kbuf, vt, out);
}